// Round 1
// baseline (447.451 us; speedup 1.0000x reference)
//
#include <hip/hip_runtime.h>
#include <hip/hip_bf16.h>
#include <math.h>

// Problem constants (fixed by setup_inputs)
#define DIMX 48      // dim
#define HID  16      // hid
#define CCH  8       // C = hid/2
#define BB   16      // batch
#define HH   256
#define WW   256
#define HWPIX (HH * WW)            // 65536
#define NPIX  (BB * HWPIX)         // 1048576
#define LN_EPS 1e-5f

__device__ __forceinline__ float gelu_exact(float v) {
    // x * 0.5 * (1 + erf(x / sqrt(2)))
    return 0.5f * v * (1.0f + erff(v * 0.70710678118654752f));
}

// Stage 1: per-pixel  y = gelu(gelu(x @ W1 + b1)); x1 = y[:8]; n = LN(y[8:16])
// x rows are contiguous 48 floats per pixel (flat reinterpret of NCHW).
__global__ __launch_bounds__(256) void stage1_kernel(
    const float* __restrict__ x,
    const float* __restrict__ W1,     // (48,16) row-major
    const float* __restrict__ b1,     // (16)
    const float* __restrict__ gamma,  // (8)
    const float* __restrict__ beta,   // (8)
    float* __restrict__ ws_x1,        // (NPIX, 8)
    float* __restrict__ ws_n)         // (NPIX, 8)
{
    __shared__ float sW1[DIMX * HID];   // 768
    __shared__ float sb1[HID];
    __shared__ float sg[CCH];
    __shared__ float sb[CCH];

    const int t = threadIdx.x;
    for (int i = t; i < DIMX * HID; i += 256) sW1[i] = W1[i];
    if (t < HID) sb1[t] = b1[t];
    if (t < CCH) { sg[t] = gamma[t]; sb[t] = beta[t]; }
    __syncthreads();

    const int p = blockIdx.x * 256 + t;
    if (p >= NPIX) return;

    // load 48 contiguous floats (12 x float4)
    const float4* __restrict__ xp = (const float4*)(x + (size_t)p * DIMX);
    float xv[DIMX];
#pragma unroll
    for (int i = 0; i < DIMX / 4; ++i) {
        float4 v = xp[i];
        xv[i * 4 + 0] = v.x; xv[i * 4 + 1] = v.y;
        xv[i * 4 + 2] = v.z; xv[i * 4 + 3] = v.w;
    }

    // y = x @ W1 + b1
    float y[HID];
#pragma unroll
    for (int j = 0; j < HID; ++j) y[j] = sb1[j];
#pragma unroll 4
    for (int k = 0; k < DIMX; ++k) {
        const float xk = xv[k];
        const float* wrow = &sW1[k * HID];
#pragma unroll
        for (int j = 0; j < HID; ++j) y[j] = fmaf(xk, wrow[j], y[j]);
    }

    // double exact gelu
#pragma unroll
    for (int j = 0; j < HID; ++j) y[j] = gelu_exact(gelu_exact(y[j]));

    // layernorm over y[8..15]
    float m = 0.f;
#pragma unroll
    for (int c = 0; c < CCH; ++c) m += y[CCH + c];
    m *= (1.0f / CCH);
    float var = 0.f;
#pragma unroll
    for (int c = 0; c < CCH; ++c) {
        float d = y[CCH + c] - m;
        var = fmaf(d, d, var);
    }
    var *= (1.0f / CCH);
    const float rs = rsqrtf(var + LN_EPS);

    float nvals[CCH];
#pragma unroll
    for (int c = 0; c < CCH; ++c)
        nvals[c] = fmaf((y[CCH + c] - m) * rs, sg[c], sb[c]);

    // store x1 (8 floats) and n (8 floats), vectorized
    float4* o1 = (float4*)(ws_x1 + (size_t)p * CCH);
    o1[0] = make_float4(y[0], y[1], y[2], y[3]);
    o1[1] = make_float4(y[4], y[5], y[6], y[7]);
    float4* on = (float4*)(ws_n + (size_t)p * CCH);
    on[0] = make_float4(nvals[0], nvals[1], nvals[2], nvals[3]);
    on[1] = make_float4(nvals[4], nvals[5], nvals[6], nvals[7]);
}

// Stage 2: depthwise 3x3 (SAME, zero pad) + pointwise 1x1 on n; g = x1*sp*ch;
// out = g @ W2 + b2, scattered to (B, 48, H, W).
__global__ __launch_bounds__(256) void stage2_kernel(
    const float* __restrict__ ws_x1,
    const float* __restrict__ ws_n,
    const float* __restrict__ dw_w,   // (8,1,3,3)
    const float* __restrict__ dw_b,   // (8)
    const float* __restrict__ pw_w,   // (8,8)
    const float* __restrict__ pw_b,   // (8)
    const float* __restrict__ W2,     // (8,48)
    const float* __restrict__ b2,     // (48)
    float* __restrict__ out)          // (B,48,H,W)
{
    __shared__ float sdw[CCH * 9];      // 72
    __shared__ float sdwb[CCH];
    __shared__ float spw[CCH * CCH];    // 64
    __shared__ float spwb[CCH];
    __shared__ float sW2[CCH * DIMX];   // 384
    __shared__ float sb2[DIMX];

    const int t = threadIdx.x;
    if (t < CCH * 9) sdw[t] = dw_w[t];
    if (t < CCH) { sdwb[t] = dw_b[t]; spwb[t] = pw_b[t]; }
    if (t >= 128 && t < 128 + CCH * CCH) spw[t - 128] = pw_w[t - 128];
    for (int i = t; i < CCH * DIMX; i += 256) sW2[i] = W2[i];
    if (t >= 192 && t < 192 + DIMX) sb2[t - 192] = b2[t - 192];
    __syncthreads();

    const int p = blockIdx.x * 256 + t;
    if (p >= NPIX) return;
    const int b = p >> 16;          // / HWPIX
    const int s = p & (HWPIX - 1);
    const int h = s >> 8;
    const int w = s & (WW - 1);

    // depthwise conv accumulation (zero padding outside)
    float sp[CCH];
#pragma unroll
    for (int c = 0; c < CCH; ++c) sp[c] = sdwb[c];

    float nc[CCH];  // center n, for pointwise

#pragma unroll
    for (int dh = -1; dh <= 1; ++dh) {
        const int hh = h + dh;
        if (hh < 0 || hh >= HH) continue;
#pragma unroll
        for (int dw = -1; dw <= 1; ++dw) {
            const int wcol = w + dw;
            if (wcol < 0 || wcol >= WW) continue;
            const float4* nb = (const float4*)(ws_n + ((size_t)p + dh * WW + dw) * CCH);
            float4 a = nb[0], c4 = nb[1];
            float nv[CCH] = {a.x, a.y, a.z, a.w, c4.x, c4.y, c4.z, c4.w};
            const int ki = (dh + 1) * 3 + (dw + 1);
#pragma unroll
            for (int c = 0; c < CCH; ++c)
                sp[c] = fmaf(nv[c], sdw[c * 9 + ki], sp[c]);
            if (dh == 0 && dw == 0) {
#pragma unroll
                for (int c = 0; c < CCH; ++c) nc[c] = nv[c];
            }
        }
    }

    // pointwise conv on center
    float ch[CCH];
#pragma unroll
    for (int co = 0; co < CCH; ++co) {
        float acc = spwb[co];
#pragma unroll
        for (int ci = 0; ci < CCH; ++ci)
            acc = fmaf(nc[ci], spw[co * CCH + ci], acc);
        ch[co] = acc;
    }

    // gate with x1
    const float4* x1p = (const float4*)(ws_x1 + (size_t)p * CCH);
    float4 xa = x1p[0], xb = x1p[1];
    float x1v[CCH] = {xa.x, xa.y, xa.z, xa.w, xb.x, xb.y, xb.z, xb.w};
    float g[CCH];
#pragma unroll
    for (int c = 0; c < CCH; ++c) g[c] = x1v[c] * (sp[c] * ch[c]);

    // out[d] = sum_c g[c] * W2[c,d] + b2[d]; coalesced per-d stores
    float* obase = out + (size_t)b * DIMX * HWPIX + s;
#pragma unroll 8
    for (int d = 0; d < DIMX; ++d) {
        float acc = sb2[d];
#pragma unroll
        for (int c = 0; c < CCH; ++c)
            acc = fmaf(g[c], sW2[c * DIMX + d], acc);
        obase[(size_t)d * HWPIX] = acc;
    }
}

extern "C" void kernel_launch(void* const* d_in, const int* in_sizes, int n_in,
                              void* d_out, int out_size, void* d_ws, size_t ws_size,
                              hipStream_t stream) {
    const float* x     = (const float*)d_in[0];
    const float* W1    = (const float*)d_in[1];
    const float* b1    = (const float*)d_in[2];
    const float* gamma = (const float*)d_in[3];
    const float* beta  = (const float*)d_in[4];
    const float* dw_w  = (const float*)d_in[5];
    const float* dw_b  = (const float*)d_in[6];
    const float* pw_w  = (const float*)d_in[7];
    const float* pw_b  = (const float*)d_in[8];
    const float* W2    = (const float*)d_in[9];
    const float* b2    = (const float*)d_in[10];
    float* out = (float*)d_out;

    float* ws_n  = (float*)d_ws;                       // NPIX*8 floats = 33.5 MB
    float* ws_x1 = ws_n + (size_t)NPIX * CCH;          // NPIX*8 floats = 33.5 MB

    const int blocks = NPIX / 256;  // 4096
    stage1_kernel<<<blocks, 256, 0, stream>>>(x, W1, b1, gamma, beta, ws_x1, ws_n);
    stage2_kernel<<<blocks, 256, 0, stream>>>(ws_x1, ws_n, dw_w, dw_b, pw_w, pw_b,
                                              W2, b2, out);
}